// Round 3
// baseline (7720.277 us; speedup 1.0000x reference)
//
#include <hip/hip_runtime.h>
#include <hip/hip_bf16.h>

typedef unsigned short u16;
typedef unsigned int   u32;
typedef __attribute__((ext_vector_type(8))) short bf16x8;
typedef __attribute__((ext_vector_type(4))) float f32x4;

#define NH   16
#define SS   2048

__device__ __forceinline__ u16 bf16b(float f) {
  union { float f; u32 u; } v; v.f = f;
  u32 r = (v.u + 0x7fffu + ((v.u >> 16) & 1u)) >> 16;
  return (u16)r;
}
__device__ __forceinline__ float bf2f(u16 v) {
  union { u32 u; float f; } x; x.u = (u32)v << 16; return x.f;
}
__device__ __forceinline__ f32x4 mfma16(bf16x8 a, bf16x8 b, f32x4 c) {
  return __builtin_amdgcn_mfma_f32_16x16x32_bf16(a, b, c, 0, 0, 0);
}

// ---------------------------------------------------------------- zero-fill (ws-too-small signature)
__global__ __launch_bounds__(256) void zerok(float* __restrict__ p, long n)
{
  long i = ((long)blockIdx.x * 256 + threadIdx.x) * 4;
  if (i < n) { p[i] = 0.f; p[i+1] = 0.f; p[i+2] = 0.f; p[i+3] = 0.f; }
}

// ---------------------------------------------------------------- cast fp32->bf16
__global__ __launch_bounds__(256) void castk(const float* __restrict__ src,
                                             u16* __restrict__ dst, long n)
{
  long i = ((long)blockIdx.x * 256 + threadIdx.x) * 4;
  if (i >= n) return;
  const float4 f = *(const float4*)(src + i);
  uint2 v;
  v.x = (u32)bf16b(f.x) | ((u32)bf16b(f.y) << 16);
  v.y = (u32)bf16b(f.z) | ((u32)bf16b(f.w) << 16);
  *(uint2*)(dst + i) = v;
}

// ---------------------------------------------------------------- split wkv_b
// T1[h][c][d] = wkv_b[(h*256+d)*512 + c]   (nope, transposed -> B^T GEMM form)
// Wv[h][d][c] = wkv_b[(h*256+128+d)*512+c] (v part)
__global__ __launch_bounds__(256) void wsplit(const float* __restrict__ wb,
                                              u16* __restrict__ T1, u16* __restrict__ Wv)
{
  const long i = (long)blockIdx.x * 256 + threadIdx.x;   // < 16*65536
  const int h   = (int)(i >> 16);
  const int rem = (int)(i & 65535);
  { const int c = rem >> 7, d = rem & 127;
    T1[i] = bf16b(wb[((long)(h * 256 + d)) * 512 + c]); }
  { const int d = rem >> 9, c = rem & 511;
    Wv[i] = bf16b(wb[((long)(h * 256 + 128 + d)) * 512 + c]); }
}

// ---------------------------------------------------------------- generic bf16 GEMM  C = A @ W^T
template<int OUTBF>
__global__ __launch_bounds__(256, 2)
void gemm_bt(const u16* __restrict__ A, const u16* __restrict__ W, void* __restrict__ Cout,
             int M, int N, int K, int lda, int ldw, int ldc,
             long aStride, long wStride, long cStride)
{
  __shared__ u16 As[128 * 40];
  __shared__ u16 Bs[128 * 40];
  const int tid = threadIdx.x;
  const int wave = tid >> 6, lane = tid & 63, g = lane >> 4, l15 = lane & 15;
  const int z = blockIdx.z;
  A += (long)z * aStride;  W += (long)z * wStride;
  const long cOff = (long)z * cStride;
  const int m0 = blockIdx.y * 128, n0 = blockIdx.x * 128;
  const int mq = (wave >> 1) * 64, nq = (wave & 1) * 64;
  const int srow = tid >> 1, scol = (tid & 1) * 16;

  const f32x4 fzero = {0.f, 0.f, 0.f, 0.f};
  f32x4 acc[4][4];
#pragma unroll
  for (int i = 0; i < 4; i++)
#pragma unroll
    for (int j = 0; j < 4; j++) acc[i][j] = fzero;

  for (int k0 = 0; k0 < K; k0 += 32) {
    const u16* aSrc = A + (long)(m0 + srow) * lda + k0 + scol;
    uint4 av0 = *(const uint4*)aSrc;
    uint4 av1 = *(const uint4*)(aSrc + 8);
    uint4 bv0 = make_uint4(0, 0, 0, 0), bv1 = make_uint4(0, 0, 0, 0);
    if (n0 + srow < N) {
      const u16* wSrc = W + (long)(n0 + srow) * ldw + k0 + scol;
      bv0 = *(const uint4*)wSrc;
      bv1 = *(const uint4*)(wSrc + 8);
    }
    __syncthreads();
    *(uint4*)&As[srow * 40 + scol]     = av0;
    *(uint4*)&As[srow * 40 + scol + 8] = av1;
    *(uint4*)&Bs[srow * 40 + scol]     = bv0;
    *(uint4*)&Bs[srow * 40 + scol + 8] = bv1;
    __syncthreads();

    bf16x8 af[4], bfr[4];
#pragma unroll
    for (int i = 0; i < 4; i++) af[i]  = *(const bf16x8*)&As[(mq + i * 16 + l15) * 40 + g * 8];
#pragma unroll
    for (int j = 0; j < 4; j++) bfr[j] = *(const bf16x8*)&Bs[(nq + j * 16 + l15) * 40 + g * 8];
#pragma unroll
    for (int i = 0; i < 4; i++)
#pragma unroll
      for (int j = 0; j < 4; j++)
        acc[i][j] = mfma16(af[i], bfr[j], acc[i][j]);
  }

#pragma unroll
  for (int i = 0; i < 4; i++) {
    const int r0 = m0 + mq + i * 16 + g * 4;
#pragma unroll
    for (int j = 0; j < 4; j++) {
      const int c = n0 + nq + j * 16 + l15;
      if (c < N) {
#pragma unroll
        for (int r = 0; r < 4; r++) {
          const long idx = cOff + (long)(r0 + r) * ldc + c;
          if (OUTBF) ((u16*)Cout)[idx]   = bf16b(acc[i][j][r]);
          else       ((float*)Cout)[idx] = acc[i][j][r];
        }
      }
    }
  }
}

// ---------------------------------------------------------------- q rope pack (bf16 q in, bf16 roped qpe out)
__global__ __launch_bounds__(256) void qpack(const u16* __restrict__ q,
                                             const float* __restrict__ angles,
                                             u16* __restrict__ qpe)
{
  const int s = blockIdx.x;
  const int sseq = s & (SS - 1);
  const int tid = threadIdx.x;
#pragma unroll
  for (int pp = 0; pp < 2; pp++) {
    const int p = tid * 2 + pp;           // 0..511 pair index
    const int h = p >> 5, j = p & 31;
    const float xr = bf2f(q[(long)s * 3072 + h * 192 + 128 + 2 * j]);
    const float xi = bf2f(q[(long)s * 3072 + h * 192 + 128 + 2 * j + 1]);
    float sn, cs;
    __sincosf(angles[sseq * 32 + j], &sn, &cs);
    const u32 pk = (u32)bf16b(xr * cs - xi * sn) | ((u32)bf16b(xr * sn + xi * cs) << 16);
    *(u32*)(qpe + ((long)s * NH + h) * 64 + 2 * j) = pk;
  }
}

// ---------------------------------------------------------------- kv pack: rmsnorm(kv_c)->bf16, rope(k_pe)->bf16
__global__ __launch_bounds__(256) void kvpack(const u16* __restrict__ kv,
                                              const float* __restrict__ angles,
                                              const float* __restrict__ kvw,
                                              u16* __restrict__ cb, u16* __restrict__ kpe)
{
  const int row = blockIdx.x * 4 + (threadIdx.x >> 6);
  const int lane = threadIdx.x & 63;
  const int sseq = row & (SS - 1);
  const u16* src = kv + (long)row * 576;
  float v[8]; float ss = 0.f;
#pragma unroll
  for (int j = 0; j < 8; j++) { float t = bf2f(src[lane + j * 64]); v[j] = t; ss += t * t; }
#pragma unroll
  for (int d = 1; d < 64; d <<= 1) ss += __shfl_xor(ss, d, 64);
  const float rn = 1.0f / sqrtf(ss * (1.f / 512.f) + 1e-6f);
#pragma unroll
  for (int j = 0; j < 8; j++)
    cb[(long)row * 512 + lane + j * 64] = bf16b(v[j] * rn * kvw[lane + j * 64]);
  if (lane < 32) {
    const float xr = bf2f(src[512 + 2 * lane]), xi = bf2f(src[512 + 2 * lane + 1]);
    float sn, cs;
    __sincosf(angles[sseq * 32 + lane], &sn, &cs);
    const u32 pk = (u32)bf16b(xr * cs - xi * sn) | ((u32)bf16b(xr * sn + xi * cs) << 16);
    *(u32*)(kpe + (long)row * 64 + 2 * lane) = pk;
  }
}

// ---------------------------------------------------------------- attention: one wave per (b,h, 8 q-rows)
// score = q_abs . c + q_pe . k_pe ; fp32 online softmax; o = sum p*c / l
__global__ __launch_bounds__(64)
void attn8(const u16* __restrict__ qab, const u16* __restrict__ qpe,
           const u16* __restrict__ cb, const u16* __restrict__ kpe,
           u16* __restrict__ olat)
{
  const int lane = threadIdx.x;
  const int s0 = blockIdx.x * 8;
  const int bh = blockIdx.y, b = bh >> 4, h = bh & 15;
  const float SC = 0.07216878364870323f * 1.3688879454113936f * 1.3688879454113936f;
  const float NEG_INF = -__builtin_inff();

  float qlo[8][4], qhi[8][4], qp[8];
#pragma unroll
  for (int r = 0; r < 8; r++) {
    const long qbase = ((long)(b * SS + s0 + r) * NH + h) * 512;
#pragma unroll
    for (int j = 0; j < 4; j++) {
      const u32 w = *(const u32*)&qab[qbase + 2 * lane + j * 128];
      qlo[r][j] = bf2f((u16)w); qhi[r][j] = bf2f((u16)(w >> 16));
    }
    qp[r] = bf2f(qpe[((long)(b * SS + s0 + r) * NH + h) * 64 + lane]);
  }
  float olo[8][4], ohi[8][4], m[8], l[8];
#pragma unroll
  for (int r = 0; r < 8; r++) {
    m[r] = NEG_INF; l[r] = 0.f;
#pragma unroll
    for (int j = 0; j < 4; j++) { olo[r][j] = 0.f; ohi[r][j] = 0.f; }
  }

  for (int t = 0; t <= s0 + 7; ++t) {
    const long crow = (long)(b * SS + t) * 512;
    float clo[4], chi[4];
#pragma unroll
    for (int j = 0; j < 4; j++) {
      const u32 w = *(const u32*)&cb[crow + 2 * lane + j * 128];
      clo[j] = bf2f((u16)w); chi[j] = bf2f((u16)(w >> 16));
    }
    const float kp = bf2f(kpe[(long)(b * SS + t) * 64 + lane]);
#pragma unroll
    for (int r = 0; r < 8; r++) {
      float sc = qp[r] * kp;
#pragma unroll
      for (int j = 0; j < 4; j++) sc += qlo[r][j] * clo[j] + qhi[r][j] * chi[j];
#pragma unroll
      for (int d = 1; d < 64; d <<= 1) sc += __shfl_xor(sc, d, 64);
      sc = (t <= s0 + r) ? sc * SC : NEG_INF;   // first iter (t=0) always unmasked
      const float mnew = fmaxf(m[r], sc);
      const float al = __expf(m[r] - mnew);
      const float p  = __expf(sc - mnew);
      l[r] = l[r] * al + p;
      m[r] = mnew;
#pragma unroll
      for (int j = 0; j < 4; j++) {
        olo[r][j] = olo[r][j] * al + p * clo[j];
        ohi[r][j] = ohi[r][j] * al + p * chi[j];
      }
    }
  }
#pragma unroll
  for (int r = 0; r < 8; r++) {
    const float linv = 1.0f / l[r];
    u16* dst = olat + ((long)(b * SS + s0 + r) * NH + h) * 512;
#pragma unroll
    for (int j = 0; j < 4; j++) {
      const u32 w = (u32)bf16b(olo[r][j] * linv) | ((u32)bf16b(ohi[r][j] * linv) << 16);
      *(u32*)&dst[2 * lane + j * 128] = w;
    }
  }
}

// ---------------------------------------------------------------- launch
extern "C" void kernel_launch(void* const* d_in, const int* in_sizes, int n_in,
                              void* d_out, int out_size, void* d_ws, size_t ws_size,
                              hipStream_t stream)
{
  const float* x      = (const float*)d_in[0];
  const float* angles = (const float*)d_in[1];
  const float* wq     = (const float*)d_in[2];
  const float* wkv_a  = (const float*)d_in[3];
  const float* wkv_b  = (const float*)d_in[4];
  const float* wo     = (const float*)d_in[5];
  const float* kvw    = (const float*)d_in[6];

  // --- workspace plan (byte offsets; lifetimes audited against launch order) ---
  // Region A [0, 67108864): phase1 xb|kvb|wab -> phase2 qab -> phase3 ob
  // Region B [67108864, 134217728): phase1 qbf|T1|wqb -> phase2 olat
  // Persistent: wob, Wv, qpe, cbuf, kpeb.
  const size_t WS_NEED = 157810688;
  if (ws_size < WS_NEED) {           // observable signature: err == ref absmax (3.890625)
    zerok<<<dim3(8192), dim3(256), 0, stream>>>((float*)d_out, 8388608L);
    return;
  }
  char* base = (char*)d_ws;
  u16* xb   = (u16*)(base + 0);           // 16,777,216 B  [4096][2048]   dead after kv GEMM
  u16* kvb  = (u16*)(base + 16777216);    //  4,718,592 B  [4096][576]    dead after kvpack
  u16* wab  = (u16*)(base + 21495808);    //  2,359,296 B  [576][2048]    dead after kv GEMM
  u16* qab  = (u16*)(base + 0);           // 67,108,864 B  [4096][16][512]  (phase2 of A)
  u16* ob   = (u16*)(base + 0);           // 16,777,216 B  [4096][2048]     (phase3 of A)
  u16* qbf  = (u16*)(base + 67108864);    // 25,165,824 B  [4096][3072]   dead after absorb GEMM
  u16* T1   = (u16*)(base + 92274688);    //  2,097,152 B  [16][512][128] dead after absorb GEMM
  u16* wqb  = (u16*)(base + 94371840);    // 12,582,912 B  [3072][2048]   dead after q GEMM
  u16* olat = (u16*)(base + 67108864);    // 67,108,864 B  [4096][16][512]  (phase2 of B)
  u16* wob  = (u16*)(base + 134217728);   //  8,388,608 B  [2048][2048]
  u16* Wv   = (u16*)(base + 142606336);   //  2,097,152 B  [16][128][512]
  u16* qpe_ = (u16*)(base + 144703488);   //  8,388,608 B  [4096][16][64]
  u16* cbuf = (u16*)(base + 153092096);   //  4,194,304 B  [4096][512]
  u16* kpeb = (u16*)(base + 157286400);   //    524,288 B  [4096][64]

  castk<<<dim3(8192), dim3(256), 0, stream>>>(x, xb, 8388608L);
  castk<<<dim3(6144), dim3(256), 0, stream>>>(wq, wqb, 6291456L);
  castk<<<dim3(1152), dim3(256), 0, stream>>>(wkv_a, wab, 1179648L);
  castk<<<dim3(4096), dim3(256), 0, stream>>>(wo, wob, 4194304L);
  wsplit<<<dim3(4096), dim3(256), 0, stream>>>(wkv_b, T1, Wv);

  // q = x @ wq^T (bf16 out) ; kv = x @ wkv_a^T (bf16 out)
  gemm_bt<1><<<dim3(24, 32, 1), dim3(256), 0, stream>>>(
      xb, wqb, (void*)qbf, 4096, 3072, 2048, 2048, 2048, 3072, 0L, 0L, 0L);
  gemm_bt<1><<<dim3(5, 32, 1), dim3(256), 0, stream>>>(
      xb, wab, (void*)kvb, 4096, 576, 2048, 2048, 2048, 576, 0L, 0L, 0L);

  qpack<<<dim3(4096), dim3(256), 0, stream>>>(qbf, angles, qpe_);
  kvpack<<<dim3(1024), dim3(256), 0, stream>>>(kvb, angles, kvw, cbuf, kpeb);

  // q_abs[s][h][c] = q_nope[s][h][:] @ T1[h][c][:]  (A read in-place from qbf, per-head offset h*192)
  gemm_bt<1><<<dim3(4, 32, 16), dim3(256), 0, stream>>>(
      qbf, T1, (void*)qab, 4096, 512, 128, 3072, 128, 8192, 192L, 65536L, 512L);

  attn8<<<dim3(256, 32), dim3(64), 0, stream>>>(qab, qpe_, cbuf, kpeb, olat);

  // o[s][h][d] = olat[s][h][:] @ Wv[h][d][:]
  gemm_bt<1><<<dim3(1, 32, 16), dim3(256), 0, stream>>>(
      olat, Wv, (void*)ob, 4096, 128, 512, 8192, 512, 2048, 512L, 65536L, 128L);

  // out = ob @ wo^T
  gemm_bt<0><<<dim3(16, 32, 1), dim3(256), 0, stream>>>(
      ob, wob, d_out, 4096, 2048, 2048, 2048, 2048, 2048, 0L, 0L, 0L);
}

// Round 5
// 2113.575 us; speedup vs baseline: 3.6527x; 3.6527x over previous
//
#include <hip/hip_runtime.h>
#include <hip/hip_bf16.h>

typedef unsigned short u16;
typedef unsigned int   u32;
typedef __attribute__((ext_vector_type(8))) short bf16x8;
typedef __attribute__((ext_vector_type(4))) float f32x4;

#define NH   16
#define SS   2048

__device__ __forceinline__ u16 bf16b(float f) {
  union { float f; u32 u; } v; v.f = f;
  u32 r = (v.u + 0x7fffu + ((v.u >> 16) & 1u)) >> 16;
  return (u16)r;
}
__device__ __forceinline__ float bf2f(u16 v) {
  union { u32 u; float f; } x; x.u = (u32)v << 16; return x.f;
}
__device__ __forceinline__ f32x4 mfma16(bf16x8 a, bf16x8 b, f32x4 c) {
  return __builtin_amdgcn_mfma_f32_16x16x32_bf16(a, b, c, 0, 0, 0);
}

// ---------------------------------------------------------------- zero-fill (ws-too-small signature)
__global__ __launch_bounds__(256) void zerok(float* __restrict__ p, long n)
{
  long i = ((long)blockIdx.x * 256 + threadIdx.x) * 4;
  if (i < n) { p[i] = 0.f; p[i+1] = 0.f; p[i+2] = 0.f; p[i+3] = 0.f; }
}

// ---------------------------------------------------------------- cast fp32->bf16
__global__ __launch_bounds__(256) void castk(const float* __restrict__ src,
                                             u16* __restrict__ dst, long n)
{
  long i = ((long)blockIdx.x * 256 + threadIdx.x) * 4;
  if (i >= n) return;
  const float4 f = *(const float4*)(src + i);
  uint2 v;
  v.x = (u32)bf16b(f.x) | ((u32)bf16b(f.y) << 16);
  v.y = (u32)bf16b(f.z) | ((u32)bf16b(f.w) << 16);
  *(uint2*)(dst + i) = v;
}

// ---------------------------------------------------------------- split wkv_b
// T1[h][c][d] = wkv_b[(h*256+d)*512 + c]   (nope, transposed -> B^T GEMM form)
// Wv[h][d][c] = wkv_b[(h*256+128+d)*512+c] (v part)
__global__ __launch_bounds__(256) void wsplit(const float* __restrict__ wb,
                                              u16* __restrict__ T1, u16* __restrict__ Wv)
{
  const long i = (long)blockIdx.x * 256 + threadIdx.x;   // < 16*65536
  const int h   = (int)(i >> 16);
  const int rem = (int)(i & 65535);
  { const int c = rem >> 7, d = rem & 127;
    T1[i] = bf16b(wb[((long)(h * 256 + d)) * 512 + c]); }
  { const int d = rem >> 9, c = rem & 511;
    Wv[i] = bf16b(wb[((long)(h * 256 + 128 + d)) * 512 + c]); }
}

// ---------------------------------------------------------------- generic bf16 GEMM  C = A @ W^T
template<int OUTBF>
__global__ __launch_bounds__(256, 2)
void gemm_bt(const u16* __restrict__ A, const u16* __restrict__ W, void* __restrict__ Cout,
             int M, int N, int K, int lda, int ldw, int ldc,
             long aStride, long wStride, long cStride)
{
  __shared__ u16 As[128 * 40];
  __shared__ u16 Bs[128 * 40];
  const int tid = threadIdx.x;
  const int wave = tid >> 6, lane = tid & 63, g = lane >> 4, l15 = lane & 15;
  const int z = blockIdx.z;
  A += (long)z * aStride;  W += (long)z * wStride;
  const long cOff = (long)z * cStride;
  const int m0 = blockIdx.y * 128, n0 = blockIdx.x * 128;
  const int mq = (wave >> 1) * 64, nq = (wave & 1) * 64;
  const int srow = tid >> 1, scol = (tid & 1) * 16;

  const f32x4 fzero = {0.f, 0.f, 0.f, 0.f};
  f32x4 acc[4][4];
#pragma unroll
  for (int i = 0; i < 4; i++)
#pragma unroll
    for (int j = 0; j < 4; j++) acc[i][j] = fzero;

  for (int k0 = 0; k0 < K; k0 += 32) {
    const u16* aSrc = A + (long)(m0 + srow) * lda + k0 + scol;
    uint4 av0 = *(const uint4*)aSrc;
    uint4 av1 = *(const uint4*)(aSrc + 8);
    uint4 bv0 = make_uint4(0, 0, 0, 0), bv1 = make_uint4(0, 0, 0, 0);
    if (n0 + srow < N) {
      const u16* wSrc = W + (long)(n0 + srow) * ldw + k0 + scol;
      bv0 = *(const uint4*)wSrc;
      bv1 = *(const uint4*)(wSrc + 8);
    }
    __syncthreads();
    *(uint4*)&As[srow * 40 + scol]     = av0;
    *(uint4*)&As[srow * 40 + scol + 8] = av1;
    *(uint4*)&Bs[srow * 40 + scol]     = bv0;
    *(uint4*)&Bs[srow * 40 + scol + 8] = bv1;
    __syncthreads();

    bf16x8 af[4], bfr[4];
#pragma unroll
    for (int i = 0; i < 4; i++) af[i]  = *(const bf16x8*)&As[(mq + i * 16 + l15) * 40 + g * 8];
#pragma unroll
    for (int j = 0; j < 4; j++) bfr[j] = *(const bf16x8*)&Bs[(nq + j * 16 + l15) * 40 + g * 8];
#pragma unroll
    for (int i = 0; i < 4; i++)
#pragma unroll
      for (int j = 0; j < 4; j++)
        acc[i][j] = mfma16(af[i], bfr[j], acc[i][j]);
  }

#pragma unroll
  for (int i = 0; i < 4; i++) {
    const int r0 = m0 + mq + i * 16 + g * 4;
#pragma unroll
    for (int j = 0; j < 4; j++) {
      const int c = n0 + nq + j * 16 + l15;
      if (c < N) {
#pragma unroll
        for (int r = 0; r < 4; r++) {
          const long idx = cOff + (long)(r0 + r) * ldc + c;
          if (OUTBF) ((u16*)Cout)[idx]   = bf16b(acc[i][j][r]);
          else       ((float*)Cout)[idx] = acc[i][j][r];
        }
      }
    }
  }
}

// ---------------------------------------------------------------- q rope pack (bf16 q in, bf16 roped qpe out)
__global__ __launch_bounds__(256) void qpack(const u16* __restrict__ q,
                                             const float* __restrict__ angles,
                                             u16* __restrict__ qpe)
{
  const int s = blockIdx.x;
  const int sseq = s & (SS - 1);
  const int tid = threadIdx.x;
#pragma unroll
  for (int pp = 0; pp < 2; pp++) {
    const int p = tid * 2 + pp;           // 0..511 pair index
    const int h = p >> 5, j = p & 31;
    const float xr = bf2f(q[(long)s * 3072 + h * 192 + 128 + 2 * j]);
    const float xi = bf2f(q[(long)s * 3072 + h * 192 + 128 + 2 * j + 1]);
    float sn, cs;
    __sincosf(angles[sseq * 32 + j], &sn, &cs);
    const u32 pk = (u32)bf16b(xr * cs - xi * sn) | ((u32)bf16b(xr * sn + xi * cs) << 16);
    *(u32*)(qpe + ((long)s * NH + h) * 64 + 2 * j) = pk;
  }
}

// ---------------------------------------------------------------- kv pack: rmsnorm(kv_c)->bf16, rope(k_pe)->bf16
__global__ __launch_bounds__(256) void kvpack(const u16* __restrict__ kv,
                                              const float* __restrict__ angles,
                                              const float* __restrict__ kvw,
                                              u16* __restrict__ cb, u16* __restrict__ kpe)
{
  const int row = blockIdx.x * 4 + (threadIdx.x >> 6);
  const int lane = threadIdx.x & 63;
  const int sseq = row & (SS - 1);
  const u16* src = kv + (long)row * 576;
  float v[8]; float ss = 0.f;
#pragma unroll
  for (int j = 0; j < 8; j++) { float t = bf2f(src[lane + j * 64]); v[j] = t; ss += t * t; }
#pragma unroll
  for (int d = 1; d < 64; d <<= 1) ss += __shfl_xor(ss, d, 64);
  const float rn = 1.0f / sqrtf(ss * (1.f / 512.f) + 1e-6f);
#pragma unroll
  for (int j = 0; j < 8; j++)
    cb[(long)row * 512 + lane + j * 64] = bf16b(v[j] * rn * kvw[lane + j * 64]);
  if (lane < 32) {
    const float xr = bf2f(src[512 + 2 * lane]), xi = bf2f(src[512 + 2 * lane + 1]);
    float sn, cs;
    __sincosf(angles[sseq * 32 + lane], &sn, &cs);
    const u32 pk = (u32)bf16b(xr * cs - xi * sn) | ((u32)bf16b(xr * sn + xi * cs) << 16);
    *(u32*)(kpe + (long)row * 64 + 2 * lane) = pk;
  }
}

// ---------------------------------------------------------------- MFMA flash attention
// Block: 64 q-rows of one (b,h); 4 waves x 16 rows. t-tile = 16.
// S = [q_abs|q_pe] . [c|k_pe]^T via 16x16x32 MFMA (K staged row-major in Ks).
// O = P.V via 16x16x32 MFMA with P zero-padded to K=32 (Ps cols 16..31 = 0);
// V^T staged XOR-swizzled in VT; VT fully zero-initialized once so the
// k=16..31 "don't-care" B-operand region is true 0.0 (NaN-garbage * 0 = NaN
// in MFMA was the R4 failure).
__global__ __launch_bounds__(256, 2)
void attn_flash(const u16* __restrict__ qab, const u16* __restrict__ qpe,
                const u16* __restrict__ cb, const u16* __restrict__ kpe,
                u16* __restrict__ olat)
{
  __shared__ u16 Ks[16 * 584];     // [t'][c 0..511 | rope 512..575], stride 584
  __shared__ u16 VT[512 * 32];     // [c][t'^sw], sw = ((c>>2)&3)<<3, stride 32
  __shared__ u16 Ps[4][16 * 40];   // per-wave P[s'][t'], cols 16..39 stay 0

  const int tid = threadIdx.x;
  const int wave = tid >> 6, lane = tid & 63;
  const int g = lane >> 4, l15 = lane & 15;
  const int bh = blockIdx.y, b = bh >> 4, h = bh & 15;
  const int bx = blockIdx.x;
  const int s0 = bx * 64;
  const int swave = s0 + wave * 16;
  const float NEG_INF = -__builtin_inff();
  const float SC = 0.07216878364870323f * 1.3688879454113936f * 1.3688879454113936f;

  // zero-init Ps (P zero-pad cols) and the full VT (unwritten swizzle cols)
  for (int idx = tid; idx < 4 * 16 * 40 / 2; idx += 256) ((u32*)Ps)[idx] = 0;
  for (int idx = tid; idx < 512 * 32 / 2;   idx += 256) ((u32*)VT)[idx] = 0;

  // Q A-fragments: A[m=l15][k=g*8+j], k over 576 = 18 frags
  bf16x8 qf[18];
  {
    const u16* qa = qab + ((long)(b * SS + swave + l15) * NH + h) * 512;
#pragma unroll
    for (int f = 0; f < 16; f++) qf[f] = *(const bf16x8*)(qa + f * 32 + g * 8);
    const u16* qp = qpe + ((long)(b * SS + swave + l15) * NH + h) * 64;
    qf[16] = *(const bf16x8*)(qp + g * 8);
    qf[17] = *(const bf16x8*)(qp + 32 + g * 8);
  }

  const f32x4 fzero = {0.f, 0.f, 0.f, 0.f};
  f32x4 oacc[32];                 // O[s'=g*4+r][c=i*16+l15]
#pragma unroll
  for (int i = 0; i < 32; i++) oacc[i] = fzero;
  float m[4], l[4];
#pragma unroll
  for (int r = 0; r < 4; r++) { m[r] = NEG_INF; l[r] = 0.f; }

  const int nsteps = 4 * bx + 4;
  const int lastact = 4 * bx + wave;   // last tile this wave needs

  const int kr = tid >> 4, kq = tid & 15;   // Ks staging: row, col-chunk
  const int tp = tid & 7, cblk = tid >> 3;  // VT staging: t-pair, c-block

  for (int ts = 0; ts < nsteps; ++ts) {
    const int t0 = ts * 16;
    __syncthreads();
    // ---- stage Ks
    {
      const uint4* src = (const uint4*)(cb + ((long)(b * SS + t0 + kr)) * 512 + kq * 32);
      uint4* dst = (uint4*)&Ks[kr * 584 + kq * 32];
      uint4 v0 = src[0], v1 = src[1], v2 = src[2], v3 = src[3];
      dst[0] = v0; dst[1] = v1; dst[2] = v2; dst[3] = v3;
      if (kq < 8)
        *(uint4*)&Ks[kr * 584 + 512 + kq * 8] =
            *(const uint4*)(kpe + ((long)(b * SS + t0 + kr)) * 64 + kq * 8);
    }
    // ---- stage VT (transpose + XOR swizzle), 2 t's packed per dword
    {
      const u16* pa = cb + ((long)(b * SS + t0 + 2 * tp)) * 512 + cblk * 16;
      const u16* pb = pa + 512;
      uint4 a0 = ((const uint4*)pa)[0], a1 = ((const uint4*)pa)[1];
      uint4 b0 = ((const uint4*)pb)[0], b1 = ((const uint4*)pb)[1];
      u16 ua[16], ub[16];
      *(uint4*)&ua[0] = a0; *(uint4*)&ua[8] = a1;
      *(uint4*)&ub[0] = b0; *(uint4*)&ub[8] = b1;
#pragma unroll
      for (int jj = 0; jj < 16; jj++) {
        const int j = (jj + cblk) & 15;
        const int c = cblk * 16 + j;
        const int sw = ((c >> 2) & 3) << 3;
        *(u32*)&VT[c * 32 + ((2 * tp) ^ sw)] = (u32)ua[j] | ((u32)ub[j] << 16);
      }
    }
    __syncthreads();
    if (ts > lastact) continue;        // wave-uniform; barriers still hit

    // ---- S = Q K^T : D[m=s'][n=t'], B[n=l15=t'][k=c]
    f32x4 sacc = fzero;
#pragma unroll
    for (int f = 0; f < 18; f++) {
      const bf16x8 kf = *(const bf16x8*)&Ks[l15 * 584 + f * 32 + g * 8];
      sacc = mfma16(qf[f], kf, sacc);
    }

    // ---- online softmax (row s'=g*4+r owned by this lane's g-group)
    float alf[4];
#pragma unroll
    for (int r = 0; r < 4; r++) {
      const int srow = swave + g * 4 + r;
      float v = sacc[r] * SC;
      if (t0 + l15 > srow) v = NEG_INF;
      float tm = v;
#pragma unroll
      for (int d = 1; d < 16; d <<= 1) tm = fmaxf(tm, __shfl_xor(tm, d, 64));
      const float mnew = fmaxf(m[r], tm);
      const float al = __expf(m[r] - mnew);   // ts=0: exp(-inf)=0
      const float p  = __expf(v - mnew);      // masked: 0
      float rs = p;
#pragma unroll
      for (int d = 1; d < 16; d <<= 1) rs += __shfl_xor(rs, d, 64);
      l[r] = l[r] * al + rs;
      m[r] = mnew;
      alf[r] = al;
      Ps[wave][(g * 4 + r) * 40 + l15] = bf16b(p);   // intra-wave LDS, no barrier
    }

    // ---- O = P.V : A[m=s'][k=t' (0-pad 16..31)], B[n=c][k=t'] from swizzled VT
    const bf16x8 paf = *(const bf16x8*)&Ps[wave][l15 * 40 + g * 8];
#pragma unroll
    for (int i = 0; i < 32; i++) {
      const int c = i * 16 + l15;
      const int sw = ((c >> 2) & 3) << 3;
      const bf16x8 vf = *(const bf16x8*)&VT[c * 32 + ((g * 8) ^ sw)];
      f32x4 o = oacc[i];
      o[0] *= alf[0]; o[1] *= alf[1]; o[2] *= alf[2]; o[3] *= alf[3];
      oacc[i] = mfma16(paf, vf, o);
    }
  }

  // ---- epilogue: O[s][c] / l[s]
  float linv[4];
#pragma unroll
  for (int r = 0; r < 4; r++) linv[r] = 1.0f / l[r];
#pragma unroll
  for (int r = 0; r < 4; r++) {
    u16* dst = olat + ((long)(b * SS + swave + g * 4 + r) * NH + h) * 512 + l15;
#pragma unroll
    for (int i = 0; i < 32; i++)
      dst[i * 16] = bf16b(oacc[i][r] * linv[r]);
  }
}

// ---------------------------------------------------------------- launch
extern "C" void kernel_launch(void* const* d_in, const int* in_sizes, int n_in,
                              void* d_out, int out_size, void* d_ws, size_t ws_size,
                              hipStream_t stream)
{
  const float* x      = (const float*)d_in[0];
  const float* angles = (const float*)d_in[1];
  const float* wq     = (const float*)d_in[2];
  const float* wkv_a  = (const float*)d_in[3];
  const float* wkv_b  = (const float*)d_in[4];
  const float* wo     = (const float*)d_in[5];
  const float* kvw    = (const float*)d_in[6];

  // --- workspace plan (byte offsets; lifetimes audited against launch order) ---
  // Region A [0, 67108864): phase1 xb|kvb|wab -> phase2 qab -> phase3 ob
  // Region B [67108864, 134217728): phase1 qbf|T1|wqb -> phase2 olat
  // Persistent: wob, Wv, qpe, cbuf, kpeb.
  const size_t WS_NEED = 157810688;
  if (ws_size < WS_NEED) {           // observable signature: err == ref absmax (3.890625)
    zerok<<<dim3(8192), dim3(256), 0, stream>>>((float*)d_out, 8388608L);
    return;
  }
  char* base = (char*)d_ws;
  u16* xb   = (u16*)(base + 0);           // 16,777,216 B  [4096][2048]   dead after kv GEMM
  u16* kvb  = (u16*)(base + 16777216);    //  4,718,592 B  [4096][576]    dead after kvpack
  u16* wab  = (u16*)(base + 21495808);    //  2,359,296 B  [576][2048]    dead after kv GEMM
  u16* qab  = (u16*)(base + 0);           // 67,108,864 B  [4096][16][512]  (phase2 of A)
  u16* ob   = (u16*)(base + 0);           // 16,777,216 B  [4096][2048]     (phase3 of A)
  u16* qbf  = (u16*)(base + 67108864);    // 25,165,824 B  [4096][3072]   dead after absorb GEMM
  u16* T1   = (u16*)(base + 92274688);    //  2,097,152 B  [16][512][128] dead after absorb GEMM
  u16* wqb  = (u16*)(base + 94371840);    // 12,582,912 B  [3072][2048]   dead after q GEMM
  u16* olat = (u16*)(base + 67108864);    // 67,108,864 B  [4096][16][512]  (phase2 of B)
  u16* wob  = (u16*)(base + 134217728);   //  8,388,608 B  [2048][2048]
  u16* Wv   = (u16*)(base + 142606336);   //  2,097,152 B  [16][128][512]
  u16* qpe_ = (u16*)(base + 144703488);   //  8,388,608 B  [4096][16][64]
  u16* cbuf = (u16*)(base + 153092096);   //  4,194,304 B  [4096][512]
  u16* kpeb = (u16*)(base + 157286400);   //    524,288 B  [4096][64]

  castk<<<dim3(8192), dim3(256), 0, stream>>>(x, xb, 8388608L);
  castk<<<dim3(6144), dim3(256), 0, stream>>>(wq, wqb, 6291456L);
  castk<<<dim3(1152), dim3(256), 0, stream>>>(wkv_a, wab, 1179648L);
  castk<<<dim3(4096), dim3(256), 0, stream>>>(wo, wob, 4194304L);
  wsplit<<<dim3(4096), dim3(256), 0, stream>>>(wkv_b, T1, Wv);

  // q = x @ wq^T (bf16 out) ; kv = x @ wkv_a^T (bf16 out)
  gemm_bt<1><<<dim3(24, 32, 1), dim3(256), 0, stream>>>(
      xb, wqb, (void*)qbf, 4096, 3072, 2048, 2048, 2048, 3072, 0L, 0L, 0L);
  gemm_bt<1><<<dim3(5, 32, 1), dim3(256), 0, stream>>>(
      xb, wab, (void*)kvb, 4096, 576, 2048, 2048, 2048, 576, 0L, 0L, 0L);

  qpack<<<dim3(4096), dim3(256), 0, stream>>>(qbf, angles, qpe_);
  kvpack<<<dim3(1024), dim3(256), 0, stream>>>(kvb, angles, kvw, cbuf, kpeb);

  // q_abs[s][h][c] = q_nope[s][h][:] @ T1[h][c][:]  (A read in-place from qbf, per-head offset h*192)
  gemm_bt<1><<<dim3(4, 32, 16), dim3(256), 0, stream>>>(
      qbf, T1, (void*)qab, 4096, 512, 128, 3072, 128, 8192, 192L, 65536L, 512L);

  attn_flash<<<dim3(32, 32), dim3(256), 0, stream>>>(qab, qpe_, cbuf, kpeb, olat);

  // o[s][h][d] = olat[s][h][:] @ Wv[h][d][:]
  gemm_bt<1><<<dim3(1, 32, 16), dim3(256), 0, stream>>>(
      olat, Wv, (void*)ob, 4096, 128, 512, 8192, 512, 2048, 512L, 65536L, 128L);

  // out = ob @ wo^T
  gemm_bt<0><<<dim3(16, 32, 1), dim3(256), 0, stream>>>(
      ob, wob, d_out, 4096, 2048, 2048, 2048, 2048, 2048, 0L, 0L, 0L);
}